// Round 15
// baseline (126.143 us; speedup 1.0000x reference)
//
#include <hip/hip_runtime.h>
#include <math.h>

// EM routing (DigitCaps) B=16, N=16384, C=10, D=16, ITER_ROUTING=3.
// R10: LDS block-reduce + replicated acc killed the atomic tail (435->131).
// R11 (2x waves): NULL. R12 (2-row ILP): NULL. R14 (ping-pong zero-merge,
// 7 dispatches): 125.6us. pass0 == pass12 across all rounds -> limiter is
// the load-stream machinery, not VALU/shuffles/occupancy.
// R15: full-d-per-lane map. Wave = 4 rows x 16 c-slots; each lane owns a
// complete (row,c) 16-float d-vector (4 contiguous dwordx4). Per 4 rows:
// 5 vmem instrs (was 12) and ONE xor-1/2/4/8 shuffle-chain set reduces all
// 4 rows at once (c-groups = 16-lane subgroups). ~2.4x fewer vmem instrs,
// ~4x fewer shuffles per row. Finalize/ping-pong identical to R14.
//
// Thread map (256/block, 4 waves): lane=tid&63; cslot=lane&15 (c>=10
//   clamped+masked); rlane=lane>>4; row-slot=wave*4+rlane -> 16 slots,
//   16 rows each (ROWS=256).

namespace {
constexpr int BB = 16, NN = 16384, CC = 10, DD = 16;
constexpr float EPSF = 1e-9f;
constexpr int CHUNKS = 64;                   // blocks per batch b
constexpr int ROWS = NN / CHUNKS;            // 256 rows per block
// one acc replica (floats)
constexpr int ACC_SZ = BB * CC * DD * 2 + BB * CC;  // rv | rv2 | rs = 5280
constexpr int RV_OFF = 0;
constexpr int RV2_OFF = BB * CC * DD;               // 2560
constexpr int RS_OFF = 2 * BB * CC * DD;            // 5120
// par layout: miu(2560) | i2s(2560) | Asum(160) | act(160)
constexpr int PMIU = 0;
constexpr int PI2S = BB * CC * DD;                  // 2560
constexpr int PASUM = 2 * BB * CC * DD;             // 5120
constexpr int PACT = 2 * BB * CC * DD + BB * CC;    // 5280
constexpr int PAR_SZ = 2 * BB * CC * DD + 2 * BB * CC;  // 5440
// ws: 2 acc bufs x nbuf x ACC_SZ + 2 par. nbuf=4: 212480 B; nbuf=2: 128000 B
// (R10-proven); nbuf=1: 85760 B (safe floor).
}  // namespace

__global__ void zero_acc(float* acc, int n) {
  int i = blockIdx.x * blockDim.x + threadIdx.x;
  if (i < n) acc[i] = 0.0f;
}

// IT=0: r from activation only. IT=1: EM step, writes rv,rv2,rs.
// IT=2: EM step, rv,rs only.
template <int IT>
__global__ __launch_bounds__(256, 4) void pass_k(const float* __restrict__ votes,
                                                 const float* __restrict__ activ,
                                                 const float* __restrict__ par,
                                                 float* __restrict__ acc, int nbuf) {
  const int b = blockIdx.x / CHUNKS;
  const int chunk = blockIdx.x - b * CHUNKS;
  const int tid = threadIdx.x;
  const int wave = tid >> 6;
  const int lane = tid & 63;
  const int cslot = lane & 15;
  const int cc = cslot < CC ? cslot : CC - 1;
  const bool on = cslot < CC;
  const int rslot = wave * 4 + (lane >> 4);  // 0..15

  __shared__ float L_rv[4][CC][DD];
  __shared__ float L_rw[4][CC][DD];
  __shared__ float L_rs[4][CC];

  float4 mi0 = make_float4(0.f, 0.f, 0.f, 0.f), mi1 = mi0, mi2 = mi0, mi3 = mi0;
  float4 is0 = mi0, is1 = mi0, is2 = mi0, is3 = mi0;
  float Asum = 0.f, actc = 0.f;
  if (IT != 0) {
    const float* pb = par + (b * CC + cc) * DD;
    mi0 = *(const float4*)(pb + PMIU);
    mi1 = *(const float4*)(pb + PMIU + 4);
    mi2 = *(const float4*)(pb + PMIU + 8);
    mi3 = *(const float4*)(pb + PMIU + 12);
    is0 = *(const float4*)(pb + PI2S);
    is1 = *(const float4*)(pb + PI2S + 4);
    is2 = *(const float4*)(pb + PI2S + 8);
    is3 = *(const float4*)(pb + PI2S + 12);
    Asum = par[PASUM + b * CC + cc];
    actc = par[PACT + b * CC + cc];
  }

  float4 rv0 = make_float4(0.f, 0.f, 0.f, 0.f), rv1 = rv0, rv2 = rv0, rv3 = rv0;
  float4 rw0 = rv0, rw1 = rv0, rw2 = rv0, rw3 = rv0;
  float ar = 0.f;

  const int n0 = chunk * ROWS;

  for (int k = rslot; k < ROWS; k += 16) {
    const int n = n0 + k;
    const float* vb = votes + (size_t)(b * NN + n) * (CC * DD) + cc * DD;
    const float4 q0 = *(const float4*)vb;
    const float4 q1 = *(const float4*)(vb + 4);
    const float4 q2 = *(const float4*)(vb + 8);
    const float4 q3 = *(const float4*)(vb + 12);
    const float a = activ[b * NN + n];
    float r;
    if (IT == 0) {
      r = (a * (1.0f / CC)) / (a + EPSF);
      ar += r;
    } else {
      float dx, s = 0.f;
      dx = q0.x - mi0.x; s += dx * dx * is0.x;
      dx = q0.y - mi0.y; s += dx * dx * is0.y;
      dx = q0.z - mi0.z; s += dx * dx * is0.z;
      dx = q0.w - mi0.w; s += dx * dx * is0.w;
      dx = q1.x - mi1.x; s += dx * dx * is1.x;
      dx = q1.y - mi1.y; s += dx * dx * is1.y;
      dx = q1.z - mi1.z; s += dx * dx * is1.z;
      dx = q1.w - mi1.w; s += dx * dx * is1.w;
      dx = q2.x - mi2.x; s += dx * dx * is2.x;
      dx = q2.y - mi2.y; s += dx * dx * is2.y;
      dx = q2.z - mi2.z; s += dx * dx * is2.z;
      dx = q2.w - mi2.w; s += dx * dx * is2.w;
      dx = q3.x - mi3.x; s += dx * dx * is3.x;
      dx = q3.y - mi3.y; s += dx * dx * is3.y;
      dx = q3.z - mi3.z; s += dx * dx * is3.z;
      dx = q3.w - mi3.w; s += dx * dx * is3.w;
      // S_c = Asum_c - s, fully in-lane. Cross-c max+sum via xor 1,2,4,8
      // within each 16-lane c-group (4 rows reduced by the same 4 instrs).
      const float S = Asum - s;
      float M = on ? S : -1e30f;
      M = fmaxf(M, __shfl_xor(M, 1));
      M = fmaxf(M, __shfl_xor(M, 2));
      M = fmaxf(M, __shfl_xor(M, 4));
      M = fmaxf(M, __shfl_xor(M, 8));
      const float te = on ? __expf(S - M) * actc : 0.f;
      float sap = te;
      sap += __shfl_xor(sap, 1);
      sap += __shfl_xor(sap, 2);
      sap += __shfl_xor(sap, 4);
      sap += __shfl_xor(sap, 8);
      const float inv = 1.0f / (sap + EPSF);
      const float sr = a * sap * inv;  // = sum_c r before renorm
      r = (te * inv * a) / (sr + EPSF);
      ar += r;
    }
    const float t0x = r * q0.x, t0y = r * q0.y, t0z = r * q0.z, t0w = r * q0.w;
    const float t1x = r * q1.x, t1y = r * q1.y, t1z = r * q1.z, t1w = r * q1.w;
    const float t2x = r * q2.x, t2y = r * q2.y, t2z = r * q2.z, t2w = r * q2.w;
    const float t3x = r * q3.x, t3y = r * q3.y, t3z = r * q3.z, t3w = r * q3.w;
    rv0.x += t0x; rv0.y += t0y; rv0.z += t0z; rv0.w += t0w;
    rv1.x += t1x; rv1.y += t1y; rv1.z += t1z; rv1.w += t1w;
    rv2.x += t2x; rv2.y += t2y; rv2.z += t2z; rv2.w += t2w;
    rv3.x += t3x; rv3.y += t3y; rv3.z += t3z; rv3.w += t3w;
    if (IT <= 1) {
      rw0.x += t0x * q0.x; rw0.y += t0y * q0.y; rw0.z += t0z * q0.z; rw0.w += t0w * q0.w;
      rw1.x += t1x * q1.x; rw1.y += t1y * q1.y; rw1.z += t1z * q1.z; rw1.w += t1w * q1.w;
      rw2.x += t2x * q2.x; rw2.y += t2y * q2.y; rw2.z += t2z * q2.z; rw2.w += t2w * q2.w;
      rw3.x += t3x * q3.x; rw3.y += t3y * q3.y; rw3.z += t3z * q3.z; rw3.w += t3w * q3.w;
    }
  }

  // fold the 4 row-slots of this wave: lanes c, c+16, c+32, c+48 -> lane c
#define FOLD(v) v += __shfl_down(v, 32); v += __shfl_down(v, 16)
  FOLD(rv0.x); FOLD(rv0.y); FOLD(rv0.z); FOLD(rv0.w);
  FOLD(rv1.x); FOLD(rv1.y); FOLD(rv1.z); FOLD(rv1.w);
  FOLD(rv2.x); FOLD(rv2.y); FOLD(rv2.z); FOLD(rv2.w);
  FOLD(rv3.x); FOLD(rv3.y); FOLD(rv3.z); FOLD(rv3.w);
  if (IT <= 1) {
    FOLD(rw0.x); FOLD(rw0.y); FOLD(rw0.z); FOLD(rw0.w);
    FOLD(rw1.x); FOLD(rw1.y); FOLD(rw1.z); FOLD(rw1.w);
    FOLD(rw2.x); FOLD(rw2.y); FOLD(rw2.z); FOLD(rw2.w);
    FOLD(rw3.x); FOLD(rw3.y); FOLD(rw3.z); FOLD(rw3.w);
  }
  FOLD(ar);
#undef FOLD

  if (lane < CC) {  // lane == c after fold
    *(float4*)&L_rv[wave][lane][0] = rv0;
    *(float4*)&L_rv[wave][lane][4] = rv1;
    *(float4*)&L_rv[wave][lane][8] = rv2;
    *(float4*)&L_rv[wave][lane][12] = rv3;
    if (IT <= 1) {
      *(float4*)&L_rw[wave][lane][0] = rw0;
      *(float4*)&L_rw[wave][lane][4] = rw1;
      *(float4*)&L_rw[wave][lane][8] = rw2;
      *(float4*)&L_rw[wave][lane][12] = rw3;
    }
    L_rs[wave][lane] = ar;
  }
  __syncthreads();

  float* accr = acc + (size_t)(chunk % nbuf) * ACC_SZ;  // replicated lines
  if (tid < CC * DD) {
    const int tc = tid >> 4, td = tid & 15;
    const float s = L_rv[0][tc][td] + L_rv[1][tc][td] +
                    L_rv[2][tc][td] + L_rv[3][tc][td];
    atomicAdd(&accr[RV_OFF + (b * CC + tc) * DD + td], s);
    if (IT <= 1) {
      const float s2 = L_rw[0][tc][td] + L_rw[1][tc][td] +
                       L_rw[2][tc][td] + L_rw[3][tc][td];
      atomicAdd(&accr[RV2_OFF + (b * CC + tc) * DD + td], s2);
    }
  } else if (tid < CC * DD + CC) {
    const int tc = tid - CC * DD;
    const float s = L_rs[0][tc] + L_rs[1][tc] + L_rs[2][tc] + L_rs[3][tc];
    atomicAdd(&accr[RS_OFF + b * CC + tc], s);
  }
}

// MODE=0: par_out = {miu, 0.5/sig, Asum, act}; also zeroes zbuf[0..zn).
// MODE=1: out = miu. Sums nbuf acc replicas.
template <int MODE>
__global__ void finalize_k(const float* __restrict__ acc, float* __restrict__ par_out,
                           float* __restrict__ out, int nbuf,
                           float* __restrict__ zbuf, int zn) {
  const int idx = blockIdx.x * blockDim.x + threadIdx.x;
  if (idx < BB * CC * DD) {
    const int bc = idx / DD;
    float rs = 0.f, rv = 0.f;
    for (int k = 0; k < nbuf; ++k) {
      rs += acc[k * ACC_SZ + RS_OFF + bc];
      rv += acc[k * ACC_SZ + RV_OFF + idx];
    }
    const float den = rs + EPSF;
    const float miu = rv / den;
    if (MODE == 1) {
      out[idx] = miu;
    } else {
      float rv2 = 0.f;
      for (int k = 0; k < nbuf; ++k) rv2 += acc[k * ACC_SZ + RV2_OFF + idx];
      const float Sf = rs / den;
      const float sig = rv2 / den - miu * miu * (2.0f - Sf) + EPSF;
      par_out[PMIU + idx] = miu;
      par_out[PI2S + idx] = 0.5f / sig;
      if ((idx & (DD - 1)) == 0) {
        float prod = 1.0f;
        for (int d = 0; d < DD; ++d) {
          float rvd = 0.f, rv2d = 0.f;
          for (int k = 0; k < nbuf; ++k) {
            rvd += acc[k * ACC_SZ + RV_OFF + bc * DD + d];
            rv2d += acc[k * ACC_SZ + RV2_OFF + bc * DD + d];
          }
          const float m2 = rvd / den;
          const float s2 = rv2d / den - m2 * m2 * (2.0f - Sf) + EPSF;
          prod *= s2;
        }
        par_out[PASUM + bc] = -0.5f * logf(prod);
      }
    }
  }
  if (MODE == 0 && blockIdx.x == 0 && threadIdx.x < BB) {
    const int b = threadIdx.x;
    float rsv[CC];
    for (int i = 0; i < CC; ++i) {
      float s = 0.f;
      for (int k = 0; k < nbuf; ++k) s += acc[k * ACC_SZ + RS_OFF + b * CC + i];
      rsv[i] = s;
    }
    float m = -1e30f;
    for (int i = 0; i < CC; ++i) m = fmaxf(m, rsv[i]);
    float ss = 0.f;
    for (int i = 0; i < CC; ++i) ss += __expf(rsv[i] - m);
    for (int i = 0; i < CC; ++i) par_out[PACT + b * CC + i] = __expf(rsv[i] - m) / ss;
  }
  // zero the OTHER acc buffer for the next pass (disjoint from `acc`)
  if (MODE == 0) {
    const int stride = gridDim.x * blockDim.x;
    for (int i = idx; i < zn; i += stride) zbuf[i] = 0.0f;
  }
}

extern "C" void kernel_launch(void* const* d_in, const int* in_sizes, int n_in,
                              void* d_out, int out_size, void* d_ws, size_t ws_size,
                              hipStream_t stream) {
  const float* votes = (const float*)d_in[0];
  const float* activ = (const float*)d_in[1];
  // d_in[2]/d_in[3] (beta_v, beta_a) only affect the post-final act_out,
  // which never feeds the returned miu -> unused.
  float* ws = (float*)d_ws;
  float* out = (float*)d_out;

  int nbuf = 1;
  if (ws_size >= (size_t)(2 * 4 * ACC_SZ + 2 * PAR_SZ) * sizeof(float)) nbuf = 4;
  else if (ws_size >= (size_t)(2 * 2 * ACC_SZ + 2 * PAR_SZ) * sizeof(float)) nbuf = 2;

  const int accN = nbuf * ACC_SZ;
  float* accA = ws;
  float* accB = ws + accN;
  float* par0 = ws + 2 * accN;
  float* par1 = par0 + PAR_SZ;

  const dim3 gp(BB * CHUNKS), bp(256);
  const dim3 gf((BB * CC * DD + 255) / 256), bf(256);

  zero_acc<<<dim3((accN + 255) / 256), dim3(256), 0, stream>>>(accA, accN);
  pass_k<0><<<gp, bp, 0, stream>>>(votes, activ, nullptr, accA, nbuf);
  finalize_k<0><<<gf, bf, 0, stream>>>(accA, par0, nullptr, nbuf, accB, accN);
  pass_k<1><<<gp, bp, 0, stream>>>(votes, activ, par0, accB, nbuf);
  finalize_k<0><<<gf, bf, 0, stream>>>(accB, par1, nullptr, nbuf, accA, accN);
  pass_k<2><<<gp, bp, 0, stream>>>(votes, activ, par1, accA, nbuf);
  finalize_k<1><<<gf, bf, 0, stream>>>(accA, nullptr, out, nbuf, nullptr, 0);
}

// Round 17
// 125.166 us; speedup vs baseline: 1.0078x; 1.0078x over previous
//
#include <hip/hip_runtime.h>
#include <math.h>

// EM routing (DigitCaps) B=16, N=16384, C=10, D=16, ITER_ROUTING=3.
// R10: LDS block-reduce + replicated acc killed atomic tail (435->131us).
// R11 (2x waves) NULL; R12 (2-row ILP) NULL; R15 (full-d map, 2.4x fewer
// vmem instrs) NULL -> stream is memory-system-bound at ~4.7 TB/s eff
// (MSHR/concurrency, not instructions). R14 (ping-pong, 7 dispatches):
// 125.6us, best.
// R16: L3 recency probe. votes(168MB) < L3(256MB) yet FETCH=82.5MB/pass
// (~50% hits). Alternate stream direction F,R,F so each pass starts where
// the previous ended (hot end of L3). pass1 reversed at chunk AND row
// level; everything else R14-verbatim.
//
// Thread map (256/block, 4 waves): lane=tid&63; rg=lane&31; c=rg>>1
//   (c>=10 clamped+masked), half=rg&1 (owns d=8h..8h+7);
//   row-slot=(lane>>5)+2*wave -> 8 slots; 32 rows/thread as 16 x 2-row iters.

namespace {
constexpr int BB = 16, NN = 16384, CC = 10, DD = 16;
constexpr float EPSF = 1e-9f;
constexpr int CHUNKS = 64;                   // blocks per batch b
constexpr int ROWS = NN / CHUNKS;            // 256 rows per block
// one acc replica (floats)
constexpr int ACC_SZ = BB * CC * DD * 2 + BB * CC;  // rv | rv2 | rs = 5280
constexpr int RV_OFF = 0;
constexpr int RV2_OFF = BB * CC * DD;               // 2560
constexpr int RS_OFF = 2 * BB * CC * DD;            // 5120
// par layout: miu(2560) | i2s(2560) | Asum(160) | act(160)
constexpr int PMIU = 0;
constexpr int PI2S = BB * CC * DD;                  // 2560
constexpr int PASUM = 2 * BB * CC * DD;             // 5120
constexpr int PACT = 2 * BB * CC * DD + BB * CC;    // 5280
constexpr int PAR_SZ = 2 * BB * CC * DD + 2 * BB * CC;  // 5440
// ws: 2 acc bufs x nbuf x ACC_SZ + 2 par. nbuf=4: 212480 B; nbuf=2: 128000 B
// (R10-proven); nbuf=1: 85760 B (safe floor).
}  // namespace

__global__ void zero_acc(float* acc, int n) {
  int i = blockIdx.x * blockDim.x + threadIdx.x;
  if (i < n) acc[i] = 0.0f;
}

// IT=0: r from activation only. IT=1: EM step, writes rv,rv2,rs.
// IT=2: EM step, rv,rs only. REV=1: stream votes in reverse order.
template <int IT, int REV>
__global__ __launch_bounds__(256, 4) void pass_k(const float* __restrict__ votes,
                                                 const float* __restrict__ activ,
                                                 const float* __restrict__ par,
                                                 float* __restrict__ acc, int nbuf) {
  const int b = blockIdx.x / CHUNKS;
  const int chunk0 = blockIdx.x - b * CHUNKS;
  const int chunk = REV ? (CHUNKS - 1 - chunk0) : chunk0;  // reverse region map
  const int tid = threadIdx.x;
  const int wave = tid >> 6;
  const int lane = tid & 63;
  const int rg = lane & 31;
  const int c = rg >> 1;
  const int half = rg & 1;
  const int cc = c < CC ? c : CC - 1;
  const bool on = c < CC;
  const int rslot = (lane >> 5) + wave * 2;  // 0..7

  __shared__ float L_rv[4][20][8];
  __shared__ float L_rw[4][20][8];
  __shared__ float L_rs[4][CC];

  float4 mi0 = make_float4(0.f, 0.f, 0.f, 0.f), mi1 = mi0;
  float4 is0 = mi0, is1 = mi0;
  float Asum = 0.f, actc = 0.f;
  if (IT != 0) {
    const float* pb = par + (b * CC + cc) * DD + half * 8;
    mi0 = *(const float4*)(pb + PMIU);
    mi1 = *(const float4*)(pb + PMIU + 4);
    is0 = *(const float4*)(pb + PI2S);
    is1 = *(const float4*)(pb + PI2S + 4);
    Asum = par[PASUM + b * CC + cc];
    actc = par[PACT + b * CC + cc];
  }

  float4 rv0 = make_float4(0.f, 0.f, 0.f, 0.f), rv1 = rv0;
  float4 rw0 = rv0, rw1 = rv0;
  float ar = 0.f;

  const int n0 = chunk * ROWS;
  const size_t rowoff = (size_t)cc * DD + half * 8;

  for (int k = rslot; k < ROWS; k += 16) {
    // REV: walk rows back-to-front (row pairs mirrored within the block)
    const int ka = REV ? (ROWS - 1 - k) : k;
    const int kb = REV ? (ROWS - 9 - k) : (k + 8);  // k<=247 -> valid either way
    const int na = n0 + ka;
    const int nb = n0 + kb;
    const float* va = votes + (size_t)(b * NN + na) * (CC * DD) + rowoff;
    const float* vb = votes + (size_t)(b * NN + nb) * (CC * DD) + rowoff;
    const float4 qa0 = *(const float4*)va;
    const float4 qa1 = *(const float4*)(va + 4);
    const float4 qb0 = *(const float4*)vb;
    const float4 qb1 = *(const float4*)(vb + 4);
    const float aa = activ[b * NN + na];
    const float ab = activ[b * NN + nb];

    float ra, rb;
    if (IT == 0) {
      ra = (aa * (1.0f / CC)) / (aa + EPSF);
      rb = (ab * (1.0f / CC)) / (ab + EPSF);
      ar += ra + rb;
    } else {
      float dx, sa = 0.f, sb = 0.f;
      dx = qa0.x - mi0.x; sa += dx * dx * is0.x;
      dx = qa0.y - mi0.y; sa += dx * dx * is0.y;
      dx = qa0.z - mi0.z; sa += dx * dx * is0.z;
      dx = qa0.w - mi0.w; sa += dx * dx * is0.w;
      dx = qa1.x - mi1.x; sa += dx * dx * is1.x;
      dx = qa1.y - mi1.y; sa += dx * dx * is1.y;
      dx = qa1.z - mi1.z; sa += dx * dx * is1.z;
      dx = qa1.w - mi1.w; sa += dx * dx * is1.w;
      dx = qb0.x - mi0.x; sb += dx * dx * is0.x;
      dx = qb0.y - mi0.y; sb += dx * dx * is0.y;
      dx = qb0.z - mi0.z; sb += dx * dx * is0.z;
      dx = qb0.w - mi0.w; sb += dx * dx * is0.w;
      dx = qb1.x - mi1.x; sb += dx * dx * is1.x;
      dx = qb1.y - mi1.y; sb += dx * dx * is1.y;
      dx = qb1.z - mi1.z; sb += dx * dx * is1.z;
      dx = qb1.w - mi1.w; sb += dx * dx * is1.w;
      // S_c = Asum_c - sum_d dv^2*i2s; two independent shuffle chains.
      const float Sa = Asum - (sa + __shfl_xor(sa, 1));
      const float Sb = Asum - (sb + __shfl_xor(sb, 1));
      float Ma = on ? Sa : -1e30f;
      float Mb = on ? Sb : -1e30f;
      Ma = fmaxf(Ma, __shfl_xor(Ma, 2));  Mb = fmaxf(Mb, __shfl_xor(Mb, 2));
      Ma = fmaxf(Ma, __shfl_xor(Ma, 4));  Mb = fmaxf(Mb, __shfl_xor(Mb, 4));
      Ma = fmaxf(Ma, __shfl_xor(Ma, 8));  Mb = fmaxf(Mb, __shfl_xor(Mb, 8));
      Ma = fmaxf(Ma, __shfl_xor(Ma, 16)); Mb = fmaxf(Mb, __shfl_xor(Mb, 16));
      const float tea = on ? __expf(Sa - Ma) * actc : 0.f;
      const float teb = on ? __expf(Sb - Mb) * actc : 0.f;
      float sapa = tea, sapb = teb;  // sum over c (masks never cross half bit)
      sapa += __shfl_xor(sapa, 2);  sapb += __shfl_xor(sapb, 2);
      sapa += __shfl_xor(sapa, 4);  sapb += __shfl_xor(sapb, 4);
      sapa += __shfl_xor(sapa, 8);  sapb += __shfl_xor(sapb, 8);
      sapa += __shfl_xor(sapa, 16); sapb += __shfl_xor(sapb, 16);
      const float inva = 1.0f / (sapa + EPSF);
      const float invb = 1.0f / (sapb + EPSF);
      const float sra = aa * sapa * inva;  // = sum_c r before renorm
      const float srb = ab * sapb * invb;
      ra = (tea * inva * aa) / (sra + EPSF);
      rb = (teb * invb * ab) / (srb + EPSF);
      ar += ra + rb;
    }
    const float ta0x = ra * qa0.x, ta0y = ra * qa0.y, ta0z = ra * qa0.z, ta0w = ra * qa0.w;
    const float ta1x = ra * qa1.x, ta1y = ra * qa1.y, ta1z = ra * qa1.z, ta1w = ra * qa1.w;
    const float tb0x = rb * qb0.x, tb0y = rb * qb0.y, tb0z = rb * qb0.z, tb0w = rb * qb0.w;
    const float tb1x = rb * qb1.x, tb1y = rb * qb1.y, tb1z = rb * qb1.z, tb1w = rb * qb1.w;
    rv0.x += ta0x + tb0x; rv0.y += ta0y + tb0y;
    rv0.z += ta0z + tb0z; rv0.w += ta0w + tb0w;
    rv1.x += ta1x + tb1x; rv1.y += ta1y + tb1y;
    rv1.z += ta1z + tb1z; rv1.w += ta1w + tb1w;
    if (IT <= 1) {
      rw0.x += ta0x * qa0.x + tb0x * qb0.x; rw0.y += ta0y * qa0.y + tb0y * qb0.y;
      rw0.z += ta0z * qa0.z + tb0z * qb0.z; rw0.w += ta0w * qa0.w + tb0w * qb0.w;
      rw1.x += ta1x * qa1.x + tb1x * qb1.x; rw1.y += ta1y * qa1.y + tb1y * qb1.y;
      rw1.z += ta1z * qa1.z + tb1z * qb1.z; rw1.w += ta1w * qa1.w + tb1w * qb1.w;
    }
  }

  // fold the two row-slots of this wave (lane <-> lane+32)
  rv0.x += __shfl_down(rv0.x, 32); rv0.y += __shfl_down(rv0.y, 32);
  rv0.z += __shfl_down(rv0.z, 32); rv0.w += __shfl_down(rv0.w, 32);
  rv1.x += __shfl_down(rv1.x, 32); rv1.y += __shfl_down(rv1.y, 32);
  rv1.z += __shfl_down(rv1.z, 32); rv1.w += __shfl_down(rv1.w, 32);
  if (IT <= 1) {
    rw0.x += __shfl_down(rw0.x, 32); rw0.y += __shfl_down(rw0.y, 32);
    rw0.z += __shfl_down(rw0.z, 32); rw0.w += __shfl_down(rw0.w, 32);
    rw1.x += __shfl_down(rw1.x, 32); rw1.y += __shfl_down(rw1.y, 32);
    rw1.z += __shfl_down(rw1.z, 32); rw1.w += __shfl_down(rw1.w, 32);
  }
  ar += __shfl_down(ar, 32);

  // block-level reduce in LDS: one atomic set per block
  if (lane < 32 && on) {
    *(float4*)&L_rv[wave][rg][0] = rv0;
    *(float4*)&L_rv[wave][rg][4] = rv1;
    if (IT <= 1) {
      *(float4*)&L_rw[wave][rg][0] = rw0;
      *(float4*)&L_rw[wave][rg][4] = rw1;
    }
    if (half == 0) L_rs[wave][c] = ar;
  }
  __syncthreads();

  float* accr = acc + (size_t)(chunk % nbuf) * ACC_SZ;  // replicated lines
  if (tid < CC * DD) {
    const int tc = tid >> 4, td = tid & 15;
    const int rgi = tc * 2 + (td >> 3), dd = td & 7;
    const float s = L_rv[0][rgi][dd] + L_rv[1][rgi][dd] +
                    L_rv[2][rgi][dd] + L_rv[3][rgi][dd];
    atomicAdd(&accr[RV_OFF + (b * CC + tc) * DD + td], s);
    if (IT <= 1) {
      const float s2 = L_rw[0][rgi][dd] + L_rw[1][rgi][dd] +
                       L_rw[2][rgi][dd] + L_rw[3][rgi][dd];
      atomicAdd(&accr[RV2_OFF + (b * CC + tc) * DD + td], s2);
    }
  } else if (tid < CC * DD + CC) {
    const int tc = tid - CC * DD;
    const float s = L_rs[0][tc] + L_rs[1][tc] + L_rs[2][tc] + L_rs[3][tc];
    atomicAdd(&accr[RS_OFF + b * CC + tc], s);
  }
}

// MODE=0: par_out = {miu, 0.5/sig, Asum, act}; also zeroes zbuf[0..zn).
// MODE=1: out = miu. Sums nbuf acc replicas.
template <int MODE>
__global__ void finalize_k(const float* __restrict__ acc, float* __restrict__ par_out,
                           float* __restrict__ out, int nbuf,
                           float* __restrict__ zbuf, int zn) {
  const int idx = blockIdx.x * blockDim.x + threadIdx.x;
  if (idx < BB * CC * DD) {
    const int bc = idx / DD;
    float rs = 0.f, rv = 0.f;
    for (int k = 0; k < nbuf; ++k) {
      rs += acc[k * ACC_SZ + RS_OFF + bc];
      rv += acc[k * ACC_SZ + RV_OFF + idx];
    }
    const float den = rs + EPSF;
    const float miu = rv / den;
    if (MODE == 1) {
      out[idx] = miu;
    } else {
      float rv2 = 0.f;
      for (int k = 0; k < nbuf; ++k) rv2 += acc[k * ACC_SZ + RV2_OFF + idx];
      const float Sf = rs / den;
      const float sig = rv2 / den - miu * miu * (2.0f - Sf) + EPSF;
      par_out[PMIU + idx] = miu;
      par_out[PI2S + idx] = 0.5f / sig;
      if ((idx & (DD - 1)) == 0) {
        float prod = 1.0f;
        for (int d = 0; d < DD; ++d) {
          float rvd = 0.f, rv2d = 0.f;
          for (int k = 0; k < nbuf; ++k) {
            rvd += acc[k * ACC_SZ + RV_OFF + bc * DD + d];
            rv2d += acc[k * ACC_SZ + RV2_OFF + bc * DD + d];
          }
          const float m2 = rvd / den;
          const float s2 = rv2d / den - m2 * m2 * (2.0f - Sf) + EPSF;
          prod *= s2;
        }
        par_out[PASUM + bc] = -0.5f * logf(prod);
      }
    }
  }
  if (MODE == 0 && blockIdx.x == 0 && threadIdx.x < BB) {
    const int b = threadIdx.x;
    float rsv[CC];
    for (int i = 0; i < CC; ++i) {
      float s = 0.f;
      for (int k = 0; k < nbuf; ++k) s += acc[k * ACC_SZ + RS_OFF + b * CC + i];
      rsv[i] = s;
    }
    float m = -1e30f;
    for (int i = 0; i < CC; ++i) m = fmaxf(m, rsv[i]);
    float ss = 0.f;
    for (int i = 0; i < CC; ++i) ss += __expf(rsv[i] - m);
    for (int i = 0; i < CC; ++i) par_out[PACT + b * CC + i] = __expf(rsv[i] - m) / ss;
  }
  // zero the OTHER acc buffer for the next pass (disjoint from `acc`)
  if (MODE == 0) {
    const int stride = gridDim.x * blockDim.x;
    for (int i = idx; i < zn; i += stride) zbuf[i] = 0.0f;
  }
}

extern "C" void kernel_launch(void* const* d_in, const int* in_sizes, int n_in,
                              void* d_out, int out_size, void* d_ws, size_t ws_size,
                              hipStream_t stream) {
  const float* votes = (const float*)d_in[0];
  const float* activ = (const float*)d_in[1];
  // d_in[2]/d_in[3] (beta_v, beta_a) only affect the post-final act_out,
  // which never feeds the returned miu -> unused.
  float* ws = (float*)d_ws;
  float* out = (float*)d_out;

  int nbuf = 1;
  if (ws_size >= (size_t)(2 * 4 * ACC_SZ + 2 * PAR_SZ) * sizeof(float)) nbuf = 4;
  else if (ws_size >= (size_t)(2 * 2 * ACC_SZ + 2 * PAR_SZ) * sizeof(float)) nbuf = 2;

  const int accN = nbuf * ACC_SZ;
  float* accA = ws;
  float* accB = ws + accN;
  float* par0 = ws + 2 * accN;
  float* par1 = par0 + PAR_SZ;

  const dim3 gp(BB * CHUNKS), bp(256);
  const dim3 gf((BB * CC * DD + 255) / 256), bf(256);

  zero_acc<<<dim3((accN + 255) / 256), dim3(256), 0, stream>>>(accA, accN);
  pass_k<0, 0><<<gp, bp, 0, stream>>>(votes, activ, nullptr, accA, nbuf);   // fwd
  finalize_k<0><<<gf, bf, 0, stream>>>(accA, par0, nullptr, nbuf, accB, accN);
  pass_k<1, 1><<<gp, bp, 0, stream>>>(votes, activ, par0, accB, nbuf);      // rev
  finalize_k<0><<<gf, bf, 0, stream>>>(accB, par1, nullptr, nbuf, accA, accN);
  pass_k<2, 0><<<gp, bp, 0, stream>>>(votes, activ, par1, accA, nbuf);      // fwd
  finalize_k<1><<<gf, bf, 0, stream>>>(accA, nullptr, out, nbuf, nullptr, 0);
}